// Round 21
// baseline (83.437 us; speedup 1.0000x reference)
//
#include <hip/hip_runtime.h>
#include <math.h>

#define N_PTS   8192
#define F_IN    64
#define D_E     4
#define H_DIM   128
#define OUT_DIM 128
#define K_NBR   64
#define E_G     262144
#define BCAP    80     // bucket capacity (mean 32, 8.4 sigma headroom)
#define CAND 256
#define RSC 40    // chunk row stride in ushorts (80 B)
#define ARS 136   // aggbf row stride in ushorts (272 B)

typedef __attribute__((ext_vector_type(8))) short bf16x8;
typedef __attribute__((ext_vector_type(4))) float f32x4;
typedef unsigned int u32;
typedef unsigned long long u64;

__device__ __forceinline__ unsigned short f2bf(float f) {   // RNE f32->bf16
    union { float f; unsigned u; } v; v.f = f;
    unsigned r = v.u + 0x7FFFu + ((v.u >> 16) & 1u);
    return (unsigned short)(r >> 16);
}
__device__ __forceinline__ u32 pack2bf(float a, float b) {  // RNE pair
    return (u32)f2bf(a) | ((u32)f2bf(b) << 16);
}
// truncation pack: D = {hi16(b), hi16(a)} in ONE v_perm_b32
__device__ __forceinline__ u32 pack2t(float a, float b) {
    return __builtin_amdgcn_perm(__float_as_uint(b), __float_as_uint(a), 0x07060302u);
}

// fast atan2 for y >= 0; err ~1e-5 rad
__device__ __forceinline__ float fast_atan2p(float y, float x) {
    float ax = fabsf(x);
    float mn = fminf(ax, y), mx = fmaxf(ax, y);
    float rc = mx > 0.0f ? __builtin_amdgcn_rcpf(mx) : 0.0f;
    float r = mn * rc;
    float t2 = r * r;
    float p = r * (0.99997726f + t2 * (-0.33262347f + t2 * (0.19354346f +
              t2 * (-0.11643287f + t2 * (0.05265332f + t2 * (-0.01172120f))))));
    float a = (y > ax) ? (1.5707963267948966f - p) : p;
    if (x < 0.0f) a = 3.14159265358979f - a;
    return a;
}
__device__ __forceinline__ float angle3(float axv, float ayv, float azv,
                                        float bxv, float byv, float bzv) {
    float cx = ayv * bzv - azv * byv;
    float cy = azv * bxv - axv * bzv;
    float cz = axv * byv - ayv * bxv;
    float cs = cx * cx + cy * cy + cz * cz;
    float cn = cs > 0.0f ? sqrtf(cs) : 0.0f;
    float d  = axv * bxv + ayv * byv + azv * bzv;
    return fast_atan2p(cn, d);   // cn==0&&d==0 -> 0 == atan2(0,1)
}

// ---- setup: bucket build | frags + xbf + pos4/nrm4 + bounds | tail copy ----
__global__ __launch_bounds__(256) void setup_kernel(
    const int* __restrict__ ei, u32* __restrict__ bcnt, u64* __restrict__ bkt,
    const float* __restrict__ W1, const float* __restrict__ b1,
    const float* __restrict__ W2, const float* __restrict__ Wg,
    const float* __restrict__ x, const float* __restrict__ pos,
    const float* __restrict__ normal,
    const int* __restrict__ batch, int* __restrict__ bounds,
    unsigned short* __restrict__ w1f, unsigned short* __restrict__ w2f,
    unsigned short* __restrict__ wgf, unsigned short* __restrict__ xbf,
    float4* __restrict__ pos4, float4* __restrict__ nrm4,
    float* __restrict__ out) {
    int gb = blockIdx.x;
    if (gb < E_G / 256) {                       // ---- bucket build (by target)
        int e = gb * 256 + threadIdx.x;
        int j = ei[e];            // source
        int i = ei[E_G + e];      // target
        unsigned slot = atomicAdd(&bcnt[i], 1u);
        if (slot < BCAP)
            bkt[(size_t)i * BCAP + slot] = ((u64)(u32)j << 32) | (u32)e;
        return;
    }
    if (gb >= E_G / 256 + 256) {                // ---- tail: pos + batch copy
        int idx = (gb - (E_G / 256 + 256)) * 256 + threadIdx.x;
        if (idx < N_PTS * 3) out[N_PTS * OUT_DIM + idx] = pos[idx];
        else out[N_PTS * OUT_DIM + idx] = (float)batch[idx - N_PTS * 3];
        return;
    }
    int t = (gb - E_G / 256) * 256 + threadIdx.x;   // [0, 65536)
    {   // x -> bf16 (RNE), 8 elems/thread: 65536*8 = N_PTS*F_IN
        const float4* xr = (const float4*)x;
        float4 a = xr[t * 2], b = xr[t * 2 + 1];
        union { bf16x8 v; u32 d[4]; } u;
        u.d[0] = pack2bf(a.x, a.y); u.d[1] = pack2bf(a.z, a.w);
        u.d[2] = pack2bf(b.x, b.y); u.d[3] = pack2bf(b.z, b.w);
        *(bf16x8*)(xbf + (size_t)t * 8) = u.v;
    }
    if (t < N_PTS) {   // packed pos4 (w = |p|^2, same f32 ops as ref) / nrm4
        float px = pos[t * 3], py = pos[t * 3 + 1], pz = pos[t * 3 + 2];
        float4 pv; pv.x = px; pv.y = py; pv.z = pz;
        pv.w = px * px + py * py + pz * pz;
        pos4[t] = pv;
        float4 nv; nv.x = normal[t * 3]; nv.y = normal[t * 3 + 1];
        nv.z = normal[t * 3 + 2]; nv.w = 0.0f;
        nrm4[t] = nv;
    }
    if (t < 12288) {   // A-frags of W1^T: 3 kt * 8 mt * 64 lane * 8 i
        int i = t & 7, lane = (t >> 3) & 63, mt = (t >> 9) & 7, kt = t >> 12;
        int c1 = mt * 16 + (lane & 15);
        int f  = kt * 32 + (lane >> 4) * 8 + i;
        float v = 0.0f;
        if (f < 72) v = W1[f * H_DIM + c1];
        else if (f == 72) v = b1[c1];   // bias-as-feature
        w1f[t] = f2bf(v);
    }
    if (t < 16384) {   // B-frags: 4 kt * 8 nt * 64 lane * 8 i
        int i = t & 7, lane = (t >> 3) & 63, nt = (t >> 9) & 7, kt = t >> 12;
        int c = nt * 16 + (lane & 15);
        int h = kt * 32 + (lane >> 4) * 8 + i;
        w2f[t] = f2bf(W2[h * H_DIM + c]);
        wgf[t] = f2bf(Wg[h * OUT_DIM + c]);
    }
    if (gb == E_G / 256 + 255 && threadIdx.x <= 8) {   // batch bounds
        int q = threadIdx.x;
        int a = 0, c = N_PTS;
        while (a < c) { int m = (a + c) >> 1; if (batch[m] < q) a = m + 1; else c = m; }
        bounds[q] = a;
    }
}

// --- fused radius-search + msg + MFMA MLP + max-agg + final GEMV (wave=point)
// cnt is wave-uniform: slot-groups g with g*16 >= cnt are skipped entirely
// (uniform scalar branch, compile-time indices inside each unrolled copy).
__global__ __launch_bounds__(256)
__attribute__((amdgpu_waves_per_eu(2, 4)))
void mlp_kernel(
    const unsigned short* __restrict__ xbf, const float4* __restrict__ pos4,
    const float4* __restrict__ nrm4, const float* __restrict__ edge_attr,
    const u32* __restrict__ bcnt, const u64* __restrict__ bkt,
    const int* __restrict__ batch, const int* __restrict__ bounds,
    const unsigned short* __restrict__ w1f, const unsigned short* __restrict__ w2f,
    const unsigned short* __restrict__ wgf,
    const float* __restrict__ b2, const float* __restrict__ bg,
    float* __restrict__ out) {
    __shared__ __align__(16) unsigned char smem[4][4096];
    __shared__ __align__(16) unsigned short aggbf[4 * ARS];
    int tid = threadIdx.x;
    int l = tid & 63, w = tid >> 6;
    int p = blockIdx.x * 4 + w;
    int lo16 = l & 15, hi4 = l >> 4;
    unsigned char* wbase = smem[w];
    int*   nbrlist = (int*)wbase;
    int*   pkrow   = (int*)(wbase + 256);
    float* d2s     = (float*)(wbase + 1280);
    int*   js      = (int*)(wbase + 2304);
    unsigned short* cb = (unsigned short*)(wbase + 1280);

    // ---- phase A: radius ball query, x8-unrolled dwordx4 loads + ballot ----
    float4 pi4 = pos4[p];
    float pxi = pi4.x, pyi = pi4.y, pzi = pi4.z;
    float p2i = pi4.w;
    int cnt;
    {
        int b = batch[p];
        int lo = bounds[b], hi = bounds[b + 1];
        int cnt0 = 0;
        unsigned long long lmask = (1ull << l) - 1ull;
        for (int j0 = lo; j0 < hi; j0 += 512) {
            float d2v[8];
            bool  val[8];
            #pragma unroll
            for (int q = 0; q < 8; ++q) {
                int j = j0 + q * 64 + l;
                bool inb = j < hi;
                int jl = inb ? j : lo;   // clamped load; masked by inb below
                float4 pj = pos4[jl];
                float dt = pxi * pj.x + pyi * pj.y + pzi * pj.z;
                float d2 = p2i + pj.w - 2.0f * dt;   // ref formula; self -> 0
                d2v[q] = d2;
                val[q] = inb && (d2 <= 4.0f);
            }
            #pragma unroll
            for (int q = 0; q < 8; ++q) {
                unsigned long long mask = __ballot(val[q]);
                int pp = cnt0 + __popcll(mask & lmask);
                if (val[q] && pp < CAND) { d2s[pp] = d2v[q]; js[pp] = j0 + q * 64 + l; }
                cnt0 += __popcll(mask);
            }
        }
        if (cnt0 > CAND) cnt0 = CAND;
        if (cnt0 <= K_NBR) {
            nbrlist[l] = (l < cnt0) ? js[l] : -1;
        } else {
            // rare: exact top-K by (d2 asc, index asc) == jax top_k tie-break
            for (int idx = l; idx < cnt0; idx += 64) {
                float d2 = d2s[idx]; int jj = js[idx];
                int rank = 0;
                for (int u = 0; u < cnt0; ++u)
                    rank += (d2s[u] < d2) || (d2s[u] == d2 && js[u] < jj);
                if (rank < K_NBR) nbrlist[rank] = jj;
            }
            cnt0 = K_NBR;
        }
        cnt = cnt0;
    }

    // ---- early x-gather (active slot-groups only; cnt is wave-uniform) -----
    bf16x8 xfall[4][2];   // [ns][kt]
    #pragma unroll
    for (int ns = 0; ns < 4; ++ns) {
        if (ns == 0 || cnt > ns * 16) {
            int j = nbrlist[ns * 16 + lo16];
            const unsigned short* xb = xbf + (size_t)max(j, 0) * F_IN;
            xfall[ns][0] = *(const bf16x8*)(xb + hi4 * 8);
            xfall[ns][1] = *(const bf16x8*)(xb + 32 + hi4 * 8);
        }
    }

    // ---- phase B: ppf + edge_attr for own slot -----------------------------
    int jme = nbrlist[l];
    int jc = max(jme, 0);
    float4 ni4 = nrm4[p];
    float4 pj4 = pos4[jc];
    float4 nj4 = nrm4[jc];
    float nxi = ni4.x, nyi = ni4.y, nzi = ni4.z;
    float nxj = nj4.x, nyj = nj4.y, nzj = nj4.z;
    float vx = pj4.x - pxi, vy = pj4.y - pyi, vz = pj4.z - pzi;
    float sq = vx * vx + vy * vy + vz * vz;
    float dd = sq > 0.0f ? sqrtf(sq) : 0.0f;
    float a1 = angle3(nxi, nyi, nzi, vx, vy, vz);
    float a2 = angle3(nxj, nyj, nzj, vx, vy, vz);
    float a3 = angle3(nxi, nyi, nzi, nxj, nyj, nzj);
    // edge match: scan bucket[p] (wave-uniform base), min-e over src==j
    unsigned eidx = E_G;   // sentinel row
    {
        const u64* bp = bkt + (size_t)p * BCAP;
        int bc = min((int)bcnt[p], BCAP);
        for (int u0 = 0; u0 < bc; u0 += 4) {
            u64 e0 = bp[u0];
            u64 e1 = (u0 + 1 < bc) ? bp[u0 + 1] : 0xFFFFFFFFFFFFFFFFull;
            u64 e2 = (u0 + 2 < bc) ? bp[u0 + 2] : 0xFFFFFFFFFFFFFFFFull;
            u64 e3 = (u0 + 3 < bc) ? bp[u0 + 3] : 0xFFFFFFFFFFFFFFFFull;
            if ((int)(e0 >> 32) == jc) eidx = min(eidx, (unsigned)e0);
            if ((int)(e1 >> 32) == jc) eidx = min(eidx, (unsigned)e1);
            if ((int)(e2 >> 32) == jc) eidx = min(eidx, (unsigned)e2);
            if ((int)(e3 >> 32) == jc) eidx = min(eidx, (unsigned)e3);
        }
    }
    float4 er = *(const float4*)(edge_attr + (size_t)eidx * D_E);
    int4 pk;
    pk.x = (int)pack2bf(dd, a1);   pk.y = (int)pack2bf(a2, a3);
    pk.z = (int)pack2bf(er.x, er.y); pk.w = (int)pack2bf(er.z, er.w);
    ((int4*)pkrow)[l] = pk;

    // ---- layer 1 (per active group): D1 quadrants -> LDS chunk -> haf ------
    bf16x8 haf[4][4];   // [ns][kt]
    #pragma unroll
    for (int ns = 0; ns < 4; ++ns) {
        if (ns == 0 || cnt > ns * 16) {
            int slot = ns * 16 + lo16;
            int4 q = ((const int4*)pkrow)[slot];
            union { bf16x8 v; u32 d[4]; } uk;
            uk.d[0] = hi4 == 0 ? (u32)q.x : (hi4 == 1 ? 0x3F80u : 0u);
            uk.d[1] = hi4 == 0 ? (u32)q.y : 0u;
            uk.d[2] = hi4 == 0 ? (u32)q.z : 0u;
            uk.d[3] = hi4 == 0 ? (u32)q.w : 0u;
            bf16x8 ktf = uk.v;
            #pragma unroll
            for (int mtp = 0; mtp < 4; ++mtp) {
                #pragma unroll
                for (int sub = 0; sub < 2; ++sub) {
                    int mt = mtp * 2 + sub;
                    bf16x8 af0 = *(const bf16x8*)(w1f + ((0 * 8 + mt) * 64 + l) * 8);
                    bf16x8 af1 = *(const bf16x8*)(w1f + ((1 * 8 + mt) * 64 + l) * 8);
                    bf16x8 af2 = *(const bf16x8*)(w1f + ((2 * 8 + mt) * 64 + l) * 8);
                    f32x4 acc = (f32x4)0.0f;
                    acc = __builtin_amdgcn_mfma_f32_16x16x32_bf16(af0, xfall[ns][0], acc, 0, 0, 0);
                    acc = __builtin_amdgcn_mfma_f32_16x16x32_bf16(af1, xfall[ns][1], acc, 0, 0, 0);
                    acc = __builtin_amdgcn_mfma_f32_16x16x32_bf16(af2, ktf, acc, 0, 0, 0);
                    uint2 o;
                    o.x = pack2t(fmaxf(acc[0], 0.0f), fmaxf(acc[1], 0.0f));
                    o.y = pack2t(fmaxf(acc[2], 0.0f), fmaxf(acc[3], 0.0f));
                    *(uint2*)(cb + lo16 * RSC + sub * 16 + hi4 * 4) = o;
                }
                haf[ns][mtp] = *(const bf16x8*)(cb + lo16 * RSC + hi4 * 8);
            }
        }
    }

    // ---- layer 2: D2[slot][c2] = h1 @ W2 (+b2); active groups only --------
    #pragma unroll
    for (int nt = 0; nt < 8; ++nt) {
        float bb = b2[nt * 16 + lo16];
        bf16x8 bfr[4];
        #pragma unroll
        for (int kt = 0; kt < 4; ++kt)
            bfr[kt] = *(const bf16x8*)(w2f + ((kt * 8 + nt) * 64 + l) * 8);
        f32x4 acc[4];
        #pragma unroll
        for (int ms = 0; ms < 4; ++ms) { f32x4 bv = {bb, bb, bb, bb}; acc[ms] = bv; }
        #pragma unroll
        for (int ms = 0; ms < 4; ++ms) {
            if (ms == 0 || cnt > ms * 16) {
                #pragma unroll
                for (int kt = 0; kt < 4; ++kt)
                    acc[ms] = __builtin_amdgcn_mfma_f32_16x16x32_bf16(haf[ms][kt], bfr[kt], acc[ms], 0, 0, 0);
            }
        }
        // m starts at 0: max over valid of relu == max(0, max over valid)
        float m = 0.0f;
        #pragma unroll
        for (int ms = 0; ms < 4; ++ms) {
            if (ms == 0 || cnt > ms * 16) {
                #pragma unroll
                for (int r = 0; r < 4; ++r) {
                    int slot = ms * 16 + hi4 * 4 + r;
                    m = fmaxf(m, slot < cnt ? acc[ms][r] : 0.0f);
                }
            }
        }
        m = fmaxf(m, __shfl_xor(m, 16, 64));
        m = fmaxf(m, __shfl_xor(m, 32, 64));
        if ((nt >> 1) == hi4)
            aggbf[w * ARS + nt * 16 + lo16] =
                (unsigned short)(__float_as_uint(m) >> 16);
    }

    // ---- fused global_nn: out[4 pts][128] = agg @ Wg + bg ------------------
    __syncthreads();
    int arow = lo16 & 3;
    bf16x8 afr2[4];
    #pragma unroll
    for (int kt = 0; kt < 4; ++kt)
        afr2[kt] = *(const bf16x8*)(aggbf + arow * ARS + kt * 32 + hi4 * 8);
    int ntA = w * 2, ntB = w * 2 + 1;
    f32x4 accA = (f32x4)0.0f, accB = (f32x4)0.0f;
    #pragma unroll
    for (int kt = 0; kt < 4; ++kt) {
        bf16x8 bfrA = *(const bf16x8*)(wgf + ((kt * 8 + ntA) * 64 + l) * 8);
        bf16x8 bfrB = *(const bf16x8*)(wgf + ((kt * 8 + ntB) * 64 + l) * 8);
        accA = __builtin_amdgcn_mfma_f32_16x16x32_bf16(afr2[kt], bfrA, accA, 0, 0, 0);
        accB = __builtin_amdgcn_mfma_f32_16x16x32_bf16(afr2[kt], bfrB, accB, 0, 0, 0);
    }
    if (hi4 == 0) {   // C rows 0..3 = points 0..3
        int cA = ntA * 16 + lo16, cB = ntB * 16 + lo16;
        float bgA = bg[cA], bgB = bg[cB];
        size_t obase = (size_t)(blockIdx.x * 4) * OUT_DIM;
        #pragma unroll
        for (int r = 0; r < 4; ++r) {
            out[obase + (size_t)r * OUT_DIM + cA] = accA[r] + bgA;
            out[obase + (size_t)r * OUT_DIM + cB] = accB[r] + bgB;
        }
    }
}

// ---------------------------------------------------------------------------
extern "C" void kernel_launch(void* const* d_in, const int* in_sizes, int n_in,
                              void* d_out, int out_size, void* d_ws, size_t ws_size,
                              hipStream_t stream) {
    const float* x         = (const float*)d_in[0];
    const float* pos       = (const float*)d_in[1];
    const float* normal    = (const float*)d_in[2];
    const int*   batch     = (const int*)d_in[3];
    const float* edge_attr = (const float*)d_in[4];
    const int*   edge_index= (const int*)d_in[5];
    const float* W1        = (const float*)d_in[6];
    const float* b1        = (const float*)d_in[7];
    const float* W2        = (const float*)d_in[8];
    const float* b2        = (const float*)d_in[9];
    const float* Wg        = (const float*)d_in[10];
    const float* bg        = (const float*)d_in[11];
    float* out = (float*)d_out;

    unsigned char* wsb = (unsigned char*)d_ws;
    u32* bcnt = (u32*)wsb;                                      // 32 KB
    u64* bkt  = (u64*)(wsb + (size_t)N_PTS * 4);                // 5.24 MB
    unsigned short* w1f = (unsigned short*)((unsigned char*)bkt +
                          (size_t)N_PTS * BCAP * 8);
    unsigned short* w2f = w1f + 12288;
    unsigned short* wgf = w2f + 16384;
    unsigned short* xbf = wgf + 16384;                          // 1 MB
    float4* pos4 = (float4*)(xbf + (size_t)N_PTS * F_IN);       // 128 KB
    float4* nrm4 = pos4 + N_PTS;                                // 128 KB
    int* bounds = (int*)(nrm4 + N_PTS);

    hipMemsetAsync(bcnt, 0, (size_t)N_PTS * 4, stream);

    setup_kernel<<<E_G / 256 + 256 + 128, 256, 0, stream>>>(
        edge_index, bcnt, bkt, W1, b1, W2, Wg, x, pos, normal, batch, bounds,
        w1f, w2f, wgf, xbf, pos4, nrm4, out);
    mlp_kernel<<<N_PTS / 4, 256, 0, stream>>>(xbf, pos4, nrm4, edge_attr,
                                              bcnt, bkt, batch, bounds,
                                              w1f, w2f, wgf, b2, bg, out);
}

// Round 22
// 77.424 us; speedup vs baseline: 1.0777x; 1.0777x over previous
//
#include <hip/hip_runtime.h>
#include <math.h>

#define N_PTS   8192
#define F_IN    64
#define D_E     4
#define H_DIM   128
#define OUT_DIM 128
#define K_NBR   64
#define E_G     262144
#define BCAP    80     // bucket capacity (mean 32, 8.4 sigma headroom)
#define CAND 256
#define RSC 40    // chunk row stride in ushorts (80 B)
#define ARS 136   // aggbf row stride in ushorts (272 B)

typedef __attribute__((ext_vector_type(8))) short bf16x8;
typedef __attribute__((ext_vector_type(4))) float f32x4;
typedef unsigned int u32;
typedef unsigned long long u64;

__device__ __forceinline__ unsigned short f2bf(float f) {   // RNE f32->bf16
    union { float f; unsigned u; } v; v.f = f;
    unsigned r = v.u + 0x7FFFu + ((v.u >> 16) & 1u);
    return (unsigned short)(r >> 16);
}
__device__ __forceinline__ u32 pack2bf(float a, float b) {  // RNE pair
    return (u32)f2bf(a) | ((u32)f2bf(b) << 16);
}
// truncation pack: D = {hi16(b), hi16(a)} in ONE v_perm_b32
__device__ __forceinline__ u32 pack2t(float a, float b) {
    return __builtin_amdgcn_perm(__float_as_uint(b), __float_as_uint(a), 0x07060302u);
}

// fast atan2 for y >= 0; err ~1e-5 rad
__device__ __forceinline__ float fast_atan2p(float y, float x) {
    float ax = fabsf(x);
    float mn = fminf(ax, y), mx = fmaxf(ax, y);
    float rc = mx > 0.0f ? __builtin_amdgcn_rcpf(mx) : 0.0f;
    float r = mn * rc;
    float t2 = r * r;
    float p = r * (0.99997726f + t2 * (-0.33262347f + t2 * (0.19354346f +
              t2 * (-0.11643287f + t2 * (0.05265332f + t2 * (-0.01172120f))))));
    float a = (y > ax) ? (1.5707963267948966f - p) : p;
    if (x < 0.0f) a = 3.14159265358979f - a;
    return a;
}
__device__ __forceinline__ float angle3(float axv, float ayv, float azv,
                                        float bxv, float byv, float bzv) {
    float cx = ayv * bzv - azv * byv;
    float cy = azv * bxv - axv * bzv;
    float cz = axv * byv - ayv * bxv;
    float cs = cx * cx + cy * cy + cz * cz;
    float cn = cs > 0.0f ? sqrtf(cs) : 0.0f;
    float d  = axv * bxv + ayv * byv + azv * bzv;
    return fast_atan2p(cn, d);   // cn==0&&d==0 -> 0 == atan2(0,1)
}

// ---- setup: bucket build | frags + xbf + pos4/nrm4 + bounds | tail copy ----
__global__ __launch_bounds__(256) void setup_kernel(
    const int* __restrict__ ei, u32* __restrict__ bcnt, u64* __restrict__ bkt,
    const float* __restrict__ W1, const float* __restrict__ b1,
    const float* __restrict__ W2, const float* __restrict__ Wg,
    const float* __restrict__ x, const float* __restrict__ pos,
    const float* __restrict__ normal,
    const int* __restrict__ batch, int* __restrict__ bounds,
    unsigned short* __restrict__ w1f, unsigned short* __restrict__ w2f,
    unsigned short* __restrict__ wgf, unsigned short* __restrict__ xbf,
    float4* __restrict__ pos4, float4* __restrict__ nrm4,
    float* __restrict__ out) {
    int gb = blockIdx.x;
    if (gb < E_G / 256) {                       // ---- bucket build (by target)
        int e = gb * 256 + threadIdx.x;
        int j = ei[e];            // source
        int i = ei[E_G + e];      // target
        unsigned slot = atomicAdd(&bcnt[i], 1u);
        if (slot < BCAP)
            bkt[(size_t)i * BCAP + slot] = ((u64)(u32)j << 32) | (u32)e;
        return;
    }
    if (gb >= E_G / 256 + 256) {                // ---- tail: pos + batch copy
        int idx = (gb - (E_G / 256 + 256)) * 256 + threadIdx.x;
        if (idx < N_PTS * 3) out[N_PTS * OUT_DIM + idx] = pos[idx];
        else out[N_PTS * OUT_DIM + idx] = (float)batch[idx - N_PTS * 3];
        return;
    }
    int t = (gb - E_G / 256) * 256 + threadIdx.x;   // [0, 65536)
    {   // x -> bf16 (RNE), 8 elems/thread: 65536*8 = N_PTS*F_IN
        const float4* xr = (const float4*)x;
        float4 a = xr[t * 2], b = xr[t * 2 + 1];
        union { bf16x8 v; u32 d[4]; } u;
        u.d[0] = pack2bf(a.x, a.y); u.d[1] = pack2bf(a.z, a.w);
        u.d[2] = pack2bf(b.x, b.y); u.d[3] = pack2bf(b.z, b.w);
        *(bf16x8*)(xbf + (size_t)t * 8) = u.v;
    }
    if (t < N_PTS) {   // packed pos4 (w = |p|^2, same f32 ops as ref) / nrm4
        float px = pos[t * 3], py = pos[t * 3 + 1], pz = pos[t * 3 + 2];
        float4 pv; pv.x = px; pv.y = py; pv.z = pz;
        pv.w = px * px + py * py + pz * pz;
        pos4[t] = pv;
        float4 nv; nv.x = normal[t * 3]; nv.y = normal[t * 3 + 1];
        nv.z = normal[t * 3 + 2]; nv.w = 0.0f;
        nrm4[t] = nv;
    }
    if (t < 12288) {   // A-frags of W1^T: 3 kt * 8 mt * 64 lane * 8 i
        int i = t & 7, lane = (t >> 3) & 63, mt = (t >> 9) & 7, kt = t >> 12;
        int c1 = mt * 16 + (lane & 15);
        int f  = kt * 32 + (lane >> 4) * 8 + i;
        float v = 0.0f;
        if (f < 72) v = W1[f * H_DIM + c1];
        else if (f == 72) v = b1[c1];   // bias-as-feature
        w1f[t] = f2bf(v);
    }
    if (t < 16384) {   // B-frags: 4 kt * 8 nt * 64 lane * 8 i
        int i = t & 7, lane = (t >> 3) & 63, nt = (t >> 9) & 7, kt = t >> 12;
        int c = nt * 16 + (lane & 15);
        int h = kt * 32 + (lane >> 4) * 8 + i;
        w2f[t] = f2bf(W2[h * H_DIM + c]);
        wgf[t] = f2bf(Wg[h * OUT_DIM + c]);
    }
    if (gb == E_G / 256 + 255 && threadIdx.x <= 8) {   // batch bounds
        int q = threadIdx.x;
        int a = 0, c = N_PTS;
        while (a < c) { int m = (a + c) >> 1; if (batch[m] < q) a = m + 1; else c = m; }
        bounds[q] = a;
    }
}

// --- fused radius-search + msg + MFMA MLP + max-agg + final GEMV (wave=point)
// R20 structure + uniform pass-granular skip: when cnt <= 32 (wave-uniform),
// layer-1 pass 1 and layer-2 ms>=2 clusters are skipped (scalar branch).
__global__ __launch_bounds__(256)
__attribute__((amdgpu_waves_per_eu(2, 4)))
void mlp_kernel(
    const unsigned short* __restrict__ xbf, const float4* __restrict__ pos4,
    const float4* __restrict__ nrm4, const float* __restrict__ edge_attr,
    const u32* __restrict__ bcnt, const u64* __restrict__ bkt,
    const int* __restrict__ batch, const int* __restrict__ bounds,
    const unsigned short* __restrict__ w1f, const unsigned short* __restrict__ w2f,
    const unsigned short* __restrict__ wgf,
    const float* __restrict__ b2, const float* __restrict__ bg,
    float* __restrict__ out) {
    __shared__ __align__(16) unsigned char smem[4][4096];
    __shared__ __align__(16) unsigned short aggbf[4 * ARS];
    int tid = threadIdx.x;
    int l = tid & 63, w = tid >> 6;
    int p = blockIdx.x * 4 + w;
    int lo16 = l & 15, hi4 = l >> 4;
    unsigned char* wbase = smem[w];
    int*   nbrlist = (int*)wbase;
    int*   pkrow   = (int*)(wbase + 256);
    float* d2s     = (float*)(wbase + 1280);
    int*   js      = (int*)(wbase + 2304);
    unsigned short* cb = (unsigned short*)(wbase + 1280);

    // ---- phase A: radius ball query, x8-unrolled dwordx4 loads + ballot ----
    float4 pi4 = pos4[p];
    float pxi = pi4.x, pyi = pi4.y, pzi = pi4.z;
    float p2i = pi4.w;
    int cnt;
    {
        int b = batch[p];
        int lo = bounds[b], hi = bounds[b + 1];
        int cnt0 = 0;
        unsigned long long lmask = (1ull << l) - 1ull;
        for (int j0 = lo; j0 < hi; j0 += 512) {
            float d2v[8];
            bool  val[8];
            #pragma unroll
            for (int q = 0; q < 8; ++q) {
                int j = j0 + q * 64 + l;
                bool inb = j < hi;
                int jl = inb ? j : lo;   // clamped load; masked by inb below
                float4 pj = pos4[jl];
                float dt = pxi * pj.x + pyi * pj.y + pzi * pj.z;
                float d2 = p2i + pj.w - 2.0f * dt;   // ref formula; self -> 0
                d2v[q] = d2;
                val[q] = inb && (d2 <= 4.0f);
            }
            #pragma unroll
            for (int q = 0; q < 8; ++q) {
                unsigned long long mask = __ballot(val[q]);
                int pp = cnt0 + __popcll(mask & lmask);
                if (val[q] && pp < CAND) { d2s[pp] = d2v[q]; js[pp] = j0 + q * 64 + l; }
                cnt0 += __popcll(mask);
            }
        }
        if (cnt0 > CAND) cnt0 = CAND;
        if (cnt0 <= K_NBR) {
            nbrlist[l] = (l < cnt0) ? js[l] : -1;
        } else {
            // rare: exact top-K by (d2 asc, index asc) == jax top_k tie-break
            for (int idx = l; idx < cnt0; idx += 64) {
                float d2 = d2s[idx]; int jj = js[idx];
                int rank = 0;
                for (int u = 0; u < cnt0; ++u)
                    rank += (d2s[u] < d2) || (d2s[u] == d2 && js[u] < jj);
                if (rank < K_NBR) nbrlist[rank] = jj;
            }
            cnt0 = K_NBR;
        }
        cnt = cnt0;
    }
    bool big = cnt > 32;   // wave-uniform: do slots [32,64) exist?

    // ---- early x-gather issue (skip upper half when not needed) ------------
    bf16x8 xfall[4][2];   // [ns][kt]
    #pragma unroll
    for (int ns = 0; ns < 4; ++ns) {
        if (ns < 2 || big) {
            int j = nbrlist[ns * 16 + lo16];
            const unsigned short* xb = xbf + (size_t)max(j, 0) * F_IN;
            xfall[ns][0] = *(const bf16x8*)(xb + hi4 * 8);
            xfall[ns][1] = *(const bf16x8*)(xb + 32 + hi4 * 8);
        }
    }

    // ---- phase B: ppf + edge_attr for own slot -----------------------------
    int jme = nbrlist[l];
    int jc = max(jme, 0);
    float4 ni4 = nrm4[p];
    float4 pj4 = pos4[jc];
    float4 nj4 = nrm4[jc];
    float nxi = ni4.x, nyi = ni4.y, nzi = ni4.z;
    float nxj = nj4.x, nyj = nj4.y, nzj = nj4.z;
    float vx = pj4.x - pxi, vy = pj4.y - pyi, vz = pj4.z - pzi;
    float sq = vx * vx + vy * vy + vz * vz;
    float dd = sq > 0.0f ? sqrtf(sq) : 0.0f;
    float a1 = angle3(nxi, nyi, nzi, vx, vy, vz);
    float a2 = angle3(nxj, nyj, nzj, vx, vy, vz);
    float a3 = angle3(nxi, nyi, nzi, nxj, nyj, nzj);
    // edge match: scan bucket[p] (wave-uniform base), min-e over src==j
    unsigned eidx = E_G;   // sentinel row
    {
        const u64* bp = bkt + (size_t)p * BCAP;
        int bc = min((int)bcnt[p], BCAP);
        for (int u0 = 0; u0 < bc; u0 += 4) {
            u64 e0 = bp[u0];
            u64 e1 = (u0 + 1 < bc) ? bp[u0 + 1] : 0xFFFFFFFFFFFFFFFFull;
            u64 e2 = (u0 + 2 < bc) ? bp[u0 + 2] : 0xFFFFFFFFFFFFFFFFull;
            u64 e3 = (u0 + 3 < bc) ? bp[u0 + 3] : 0xFFFFFFFFFFFFFFFFull;
            if ((int)(e0 >> 32) == jc) eidx = min(eidx, (unsigned)e0);
            if ((int)(e1 >> 32) == jc) eidx = min(eidx, (unsigned)e1);
            if ((int)(e2 >> 32) == jc) eidx = min(eidx, (unsigned)e2);
            if ((int)(e3 >> 32) == jc) eidx = min(eidx, (unsigned)e3);
        }
    }
    float4 er = *(const float4*)(edge_attr + (size_t)eidx * D_E);
    int4 pk;
    pk.x = (int)pack2bf(dd, a1);   pk.y = (int)pack2bf(a2, a3);
    pk.z = (int)pack2bf(er.x, er.y); pk.w = (int)pack2bf(er.z, er.w);
    ((int4*)pkrow)[l] = pk;

    // ---- layer 1: D1[c1][slot] = W1^T @ msg^T; LDS-chunk reshuffle to haf --
    bf16x8 haf[4][4];   // [ms][kt]
    #pragma unroll
    for (int pass = 0; pass < 2; ++pass) {
        if (pass == 0 || big) {
            bf16x8 ktf[2];
            #pragma unroll
            for (int nsl = 0; nsl < 2; ++nsl) {
                int slot = (pass * 2 + nsl) * 16 + lo16;
                // kt=2 B-frag: f64..71 = ppf+eattr (hi4==0); f72 bias=1 (hi4==1)
                int4 q = ((const int4*)pkrow)[slot];
                union { bf16x8 v; u32 d[4]; } u;
                u.d[0] = hi4 == 0 ? (u32)q.x : (hi4 == 1 ? 0x3F80u : 0u);
                u.d[1] = hi4 == 0 ? (u32)q.y : 0u;
                u.d[2] = hi4 == 0 ? (u32)q.z : 0u;
                u.d[3] = hi4 == 0 ? (u32)q.w : 0u;
                ktf[nsl] = u.v;
            }
            #pragma unroll
            for (int mtp = 0; mtp < 4; ++mtp) {
                #pragma unroll
                for (int sub = 0; sub < 2; ++sub) {
                    int mt = mtp * 2 + sub;
                    bf16x8 af0 = *(const bf16x8*)(w1f + ((0 * 8 + mt) * 64 + l) * 8);
                    bf16x8 af1 = *(const bf16x8*)(w1f + ((1 * 8 + mt) * 64 + l) * 8);
                    bf16x8 af2 = *(const bf16x8*)(w1f + ((2 * 8 + mt) * 64 + l) * 8);
                    #pragma unroll
                    for (int nsl = 0; nsl < 2; ++nsl) {
                        f32x4 acc = (f32x4)0.0f;
                        acc = __builtin_amdgcn_mfma_f32_16x16x32_bf16(af0, xfall[pass * 2 + nsl][0], acc, 0, 0, 0);
                        acc = __builtin_amdgcn_mfma_f32_16x16x32_bf16(af1, xfall[pass * 2 + nsl][1], acc, 0, 0, 0);
                        acc = __builtin_amdgcn_mfma_f32_16x16x32_bf16(af2, ktf[nsl], acc, 0, 0, 0);
                        uint2 o;
                        o.x = pack2t(fmaxf(acc[0], 0.0f), fmaxf(acc[1], 0.0f));
                        o.y = pack2t(fmaxf(acc[2], 0.0f), fmaxf(acc[3], 0.0f));
                        *(uint2*)(cb + (nsl * 16 + lo16) * RSC + sub * 16 + hi4 * 4) = o;
                    }
                }
                #pragma unroll
                for (int nsl = 0; nsl < 2; ++nsl)
                    haf[pass * 2 + nsl][mtp] =
                        *(const bf16x8*)(cb + (nsl * 16 + lo16) * RSC + hi4 * 8);
            }
        }
    }

    // ---- layer 2: D2[slot][c2] = h1 @ W2 (+b2); masked relu-max over slots -
    #pragma unroll
    for (int nt = 0; nt < 8; ++nt) {
        float bb = b2[nt * 16 + lo16];
        f32x4 acc[4];
        #pragma unroll
        for (int ms = 0; ms < 4; ++ms) { f32x4 bv = {bb, bb, bb, bb}; acc[ms] = bv; }
        #pragma unroll
        for (int kt = 0; kt < 4; ++kt) {
            bf16x8 bfr = *(const bf16x8*)(w2f + ((kt * 8 + nt) * 64 + l) * 8);
            #pragma unroll
            for (int ms = 0; ms < 4; ++ms) {
                if (ms < 2 || big)
                    acc[ms] = __builtin_amdgcn_mfma_f32_16x16x32_bf16(haf[ms][kt], bfr, acc[ms], 0, 0, 0);
            }
        }
        // m starts at 0: max over valid of relu == max(0, max over valid)
        // skipped ms-groups hold bias-garbage but their slots are >= cnt -> masked
        float m = 0.0f;
        #pragma unroll
        for (int ms = 0; ms < 4; ++ms)
            #pragma unroll
            for (int r = 0; r < 4; ++r) {
                int slot = ms * 16 + hi4 * 4 + r;
                m = fmaxf(m, slot < cnt ? acc[ms][r] : 0.0f);
            }
        m = fmaxf(m, __shfl_xor(m, 16, 64));
        m = fmaxf(m, __shfl_xor(m, 32, 64));
        if ((nt >> 1) == hi4)
            aggbf[w * ARS + nt * 16 + lo16] =
                (unsigned short)(__float_as_uint(m) >> 16);
    }

    // ---- fused global_nn: out[4 pts][128] = agg @ Wg + bg ------------------
    __syncthreads();
    int arow = lo16 & 3;
    bf16x8 afr2[4];
    #pragma unroll
    for (int kt = 0; kt < 4; ++kt)
        afr2[kt] = *(const bf16x8*)(aggbf + arow * ARS + kt * 32 + hi4 * 8);
    int ntA = w * 2, ntB = w * 2 + 1;
    f32x4 accA = (f32x4)0.0f, accB = (f32x4)0.0f;
    #pragma unroll
    for (int kt = 0; kt < 4; ++kt) {
        bf16x8 bfrA = *(const bf16x8*)(wgf + ((kt * 8 + ntA) * 64 + l) * 8);
        bf16x8 bfrB = *(const bf16x8*)(wgf + ((kt * 8 + ntB) * 64 + l) * 8);
        accA = __builtin_amdgcn_mfma_f32_16x16x32_bf16(afr2[kt], bfrA, accA, 0, 0, 0);
        accB = __builtin_amdgcn_mfma_f32_16x16x32_bf16(afr2[kt], bfrB, accB, 0, 0, 0);
    }
    if (hi4 == 0) {   // C rows 0..3 = points 0..3
        int cA = ntA * 16 + lo16, cB = ntB * 16 + lo16;
        float bgA = bg[cA], bgB = bg[cB];
        size_t obase = (size_t)(blockIdx.x * 4) * OUT_DIM;
        #pragma unroll
        for (int r = 0; r < 4; ++r) {
            out[obase + (size_t)r * OUT_DIM + cA] = accA[r] + bgA;
            out[obase + (size_t)r * OUT_DIM + cB] = accB[r] + bgB;
        }
    }
}

// ---------------------------------------------------------------------------
extern "C" void kernel_launch(void* const* d_in, const int* in_sizes, int n_in,
                              void* d_out, int out_size, void* d_ws, size_t ws_size,
                              hipStream_t stream) {
    const float* x         = (const float*)d_in[0];
    const float* pos       = (const float*)d_in[1];
    const float* normal    = (const float*)d_in[2];
    const int*   batch     = (const int*)d_in[3];
    const float* edge_attr = (const float*)d_in[4];
    const int*   edge_index= (const int*)d_in[5];
    const float* W1        = (const float*)d_in[6];
    const float* b1        = (const float*)d_in[7];
    const float* W2        = (const float*)d_in[8];
    const float* b2        = (const float*)d_in[9];
    const float* Wg        = (const float*)d_in[10];
    const float* bg        = (const float*)d_in[11];
    float* out = (float*)d_out;

    unsigned char* wsb = (unsigned char*)d_ws;
    u32* bcnt = (u32*)wsb;                                      // 32 KB
    u64* bkt  = (u64*)(wsb + (size_t)N_PTS * 4);                // 5.24 MB
    unsigned short* w1f = (unsigned short*)((unsigned char*)bkt +
                          (size_t)N_PTS * BCAP * 8);
    unsigned short* w2f = w1f + 12288;
    unsigned short* wgf = w2f + 16384;
    unsigned short* xbf = wgf + 16384;                          // 1 MB
    float4* pos4 = (float4*)(xbf + (size_t)N_PTS * F_IN);       // 128 KB
    float4* nrm4 = pos4 + N_PTS;                                // 128 KB
    int* bounds = (int*)(nrm4 + N_PTS);

    hipMemsetAsync(bcnt, 0, (size_t)N_PTS * 4, stream);

    setup_kernel<<<E_G / 256 + 256 + 128, 256, 0, stream>>>(
        edge_index, bcnt, bkt, W1, b1, W2, Wg, x, pos, normal, batch, bounds,
        w1f, w2f, wgf, xbf, pos4, nrm4, out);
    mlp_kernel<<<N_PTS / 4, 256, 0, stream>>>(xbf, pos4, nrm4, edge_attr,
                                              bcnt, bkt, batch, bounds,
                                              w1f, w2f, wgf, b2, bg, out);
}

// Round 23
// 76.391 us; speedup vs baseline: 1.0922x; 1.0135x over previous
//
#include <hip/hip_runtime.h>
#include <math.h>

#define N_PTS   8192
#define F_IN    64
#define D_E     4
#define H_DIM   128
#define OUT_DIM 128
#define K_NBR   64
#define E_G     262144
#define BCAP    80     // bucket capacity (mean 32, 8.4 sigma headroom)
#define CAND 256
#define RSC 40    // chunk row stride in ushorts (80 B)
#define ARS 136   // aggbf row stride in ushorts (272 B)

typedef __attribute__((ext_vector_type(8))) short bf16x8;
typedef __attribute__((ext_vector_type(4))) float f32x4;
typedef unsigned int u32;
typedef unsigned long long u64;

__device__ __forceinline__ unsigned short f2bf(float f) {   // RNE f32->bf16
    union { float f; unsigned u; } v; v.f = f;
    unsigned r = v.u + 0x7FFFu + ((v.u >> 16) & 1u);
    return (unsigned short)(r >> 16);
}
__device__ __forceinline__ u32 pack2bf(float a, float b) {  // RNE pair
    return (u32)f2bf(a) | ((u32)f2bf(b) << 16);
}
// truncation pack: D = {hi16(b), hi16(a)} in ONE v_perm_b32
__device__ __forceinline__ u32 pack2t(float a, float b) {
    return __builtin_amdgcn_perm(__float_as_uint(b), __float_as_uint(a), 0x07060302u);
}

// fast atan2 for y >= 0; err ~1e-5 rad
__device__ __forceinline__ float fast_atan2p(float y, float x) {
    float ax = fabsf(x);
    float mn = fminf(ax, y), mx = fmaxf(ax, y);
    float rc = mx > 0.0f ? __builtin_amdgcn_rcpf(mx) : 0.0f;
    float r = mn * rc;
    float t2 = r * r;
    float p = r * (0.99997726f + t2 * (-0.33262347f + t2 * (0.19354346f +
              t2 * (-0.11643287f + t2 * (0.05265332f + t2 * (-0.01172120f))))));
    float a = (y > ax) ? (1.5707963267948966f - p) : p;
    if (x < 0.0f) a = 3.14159265358979f - a;
    return a;
}
__device__ __forceinline__ float angle3(float axv, float ayv, float azv,
                                        float bxv, float byv, float bzv) {
    float cx = ayv * bzv - azv * byv;
    float cy = azv * bxv - axv * bzv;
    float cz = axv * byv - ayv * bxv;
    float cs = cx * cx + cy * cy + cz * cz;
    float cn = cs > 0.0f ? sqrtf(cs) : 0.0f;
    float d  = axv * bxv + ayv * byv + azv * bzv;
    return fast_atan2p(cn, d);   // cn==0&&d==0 -> 0 == atan2(0,1)
}

// ---- setup: bucket build | frags + xbf + pos4/nrm4 + bounds | tail copy ----
__global__ __launch_bounds__(256) void setup_kernel(
    const int* __restrict__ ei, u32* __restrict__ bcnt, u64* __restrict__ bkt,
    const float* __restrict__ W1, const float* __restrict__ b1,
    const float* __restrict__ W2, const float* __restrict__ Wg,
    const float* __restrict__ x, const float* __restrict__ pos,
    const float* __restrict__ normal,
    const int* __restrict__ batch, int* __restrict__ bounds,
    unsigned short* __restrict__ w1f, unsigned short* __restrict__ w2f,
    unsigned short* __restrict__ wgf, unsigned short* __restrict__ xbf,
    float4* __restrict__ pos4, float4* __restrict__ nrm4,
    float* __restrict__ out) {
    int gb = blockIdx.x;
    if (gb < E_G / 256) {                       // ---- bucket build (by target)
        int e = gb * 256 + threadIdx.x;
        int j = ei[e];            // source
        int i = ei[E_G + e];      // target
        unsigned slot = atomicAdd(&bcnt[i], 1u);
        if (slot < BCAP)
            bkt[(size_t)i * BCAP + slot] = ((u64)(u32)j << 32) | (u32)e;
        return;
    }
    if (gb >= E_G / 256 + 256) {                // ---- tail: pos + batch copy
        int idx = (gb - (E_G / 256 + 256)) * 256 + threadIdx.x;
        if (idx < N_PTS * 3) out[N_PTS * OUT_DIM + idx] = pos[idx];
        else out[N_PTS * OUT_DIM + idx] = (float)batch[idx - N_PTS * 3];
        return;
    }
    int t = (gb - E_G / 256) * 256 + threadIdx.x;   // [0, 65536)
    {   // x -> bf16 (RNE), 8 elems/thread: 65536*8 = N_PTS*F_IN
        const float4* xr = (const float4*)x;
        float4 a = xr[t * 2], b = xr[t * 2 + 1];
        union { bf16x8 v; u32 d[4]; } u;
        u.d[0] = pack2bf(a.x, a.y); u.d[1] = pack2bf(a.z, a.w);
        u.d[2] = pack2bf(b.x, b.y); u.d[3] = pack2bf(b.z, b.w);
        *(bf16x8*)(xbf + (size_t)t * 8) = u.v;
    }
    if (t < N_PTS) {   // packed pos4 (w = |p|^2, same f32 ops as ref) / nrm4
        float px = pos[t * 3], py = pos[t * 3 + 1], pz = pos[t * 3 + 2];
        float4 pv; pv.x = px; pv.y = py; pv.z = pz;
        pv.w = px * px + py * py + pz * pz;
        pos4[t] = pv;
        float4 nv; nv.x = normal[t * 3]; nv.y = normal[t * 3 + 1];
        nv.z = normal[t * 3 + 2]; nv.w = 0.0f;
        nrm4[t] = nv;
    }
    if (t < 12288) {   // A-frags of W1^T: 3 kt * 8 mt * 64 lane * 8 i
        int i = t & 7, lane = (t >> 3) & 63, mt = (t >> 9) & 7, kt = t >> 12;
        int c1 = mt * 16 + (lane & 15);
        int f  = kt * 32 + (lane >> 4) * 8 + i;
        float v = 0.0f;
        if (f < 72) v = W1[f * H_DIM + c1];
        else if (f == 72) v = b1[c1];   // bias-as-feature
        w1f[t] = f2bf(v);
    }
    if (t < 16384) {   // B-frags: 4 kt * 8 nt * 64 lane * 8 i
        int i = t & 7, lane = (t >> 3) & 63, nt = (t >> 9) & 7, kt = t >> 12;
        int c = nt * 16 + (lane & 15);
        int h = kt * 32 + (lane >> 4) * 8 + i;
        w2f[t] = f2bf(W2[h * H_DIM + c]);
        wgf[t] = f2bf(Wg[h * OUT_DIM + c]);
    }
    if (gb == E_G / 256 + 255 && threadIdx.x <= 8) {   // batch bounds
        int q = threadIdx.x;
        int a = 0, c = N_PTS;
        while (a < c) { int m = (a + c) >> 1; if (batch[m] < q) a = m + 1; else c = m; }
        bounds[q] = a;
    }
}

// --- fused radius-search + msg + MFMA MLP + max-agg + final GEMV (wave=point)
// Best-measured configuration (R20): waves_per_eu(2,4), 64-reg body, phase A
// x8-unrolled dwordx4, bucket edge-match, fused Wg epilogue.
__global__ __launch_bounds__(256)
__attribute__((amdgpu_waves_per_eu(2, 4)))
void mlp_kernel(
    const unsigned short* __restrict__ xbf, const float4* __restrict__ pos4,
    const float4* __restrict__ nrm4, const float* __restrict__ edge_attr,
    const u32* __restrict__ bcnt, const u64* __restrict__ bkt,
    const int* __restrict__ batch, const int* __restrict__ bounds,
    const unsigned short* __restrict__ w1f, const unsigned short* __restrict__ w2f,
    const unsigned short* __restrict__ wgf,
    const float* __restrict__ b2, const float* __restrict__ bg,
    float* __restrict__ out) {
    __shared__ __align__(16) unsigned char smem[4][4096];
    __shared__ __align__(16) unsigned short aggbf[4 * ARS];
    int tid = threadIdx.x;
    int l = tid & 63, w = tid >> 6;
    int p = blockIdx.x * 4 + w;
    int lo16 = l & 15, hi4 = l >> 4;
    unsigned char* wbase = smem[w];
    int*   nbrlist = (int*)wbase;
    int*   pkrow   = (int*)(wbase + 256);
    float* d2s     = (float*)(wbase + 1280);
    int*   js      = (int*)(wbase + 2304);
    unsigned short* cb = (unsigned short*)(wbase + 1280);

    // ---- phase A: radius ball query, x8-unrolled dwordx4 loads + ballot ----
    float4 pi4 = pos4[p];
    float pxi = pi4.x, pyi = pi4.y, pzi = pi4.z;
    float p2i = pi4.w;
    int cnt;
    {
        int b = batch[p];
        int lo = bounds[b], hi = bounds[b + 1];
        int cnt0 = 0;
        unsigned long long lmask = (1ull << l) - 1ull;
        for (int j0 = lo; j0 < hi; j0 += 512) {
            float d2v[8];
            bool  val[8];
            #pragma unroll
            for (int q = 0; q < 8; ++q) {
                int j = j0 + q * 64 + l;
                bool inb = j < hi;
                int jl = inb ? j : lo;   // clamped load; masked by inb below
                float4 pj = pos4[jl];
                float dt = pxi * pj.x + pyi * pj.y + pzi * pj.z;
                float d2 = p2i + pj.w - 2.0f * dt;   // ref formula; self -> 0
                d2v[q] = d2;
                val[q] = inb && (d2 <= 4.0f);
            }
            #pragma unroll
            for (int q = 0; q < 8; ++q) {
                unsigned long long mask = __ballot(val[q]);
                int pp = cnt0 + __popcll(mask & lmask);
                if (val[q] && pp < CAND) { d2s[pp] = d2v[q]; js[pp] = j0 + q * 64 + l; }
                cnt0 += __popcll(mask);
            }
        }
        if (cnt0 > CAND) cnt0 = CAND;
        if (cnt0 <= K_NBR) {
            nbrlist[l] = (l < cnt0) ? js[l] : -1;
        } else {
            // rare: exact top-K by (d2 asc, index asc) == jax top_k tie-break
            for (int idx = l; idx < cnt0; idx += 64) {
                float d2 = d2s[idx]; int jj = js[idx];
                int rank = 0;
                for (int u = 0; u < cnt0; ++u)
                    rank += (d2s[u] < d2) || (d2s[u] == d2 && js[u] < jj);
                if (rank < K_NBR) nbrlist[rank] = jj;
            }
            cnt0 = K_NBR;
        }
        cnt = cnt0;
    }

    // ---- early x-gather issue: L2 latency hides under phase B's VALU chain -
    bf16x8 xfall[4][2];   // [ns][kt]
    #pragma unroll
    for (int ns = 0; ns < 4; ++ns) {
        int j = nbrlist[ns * 16 + lo16];
        const unsigned short* xb = xbf + (size_t)max(j, 0) * F_IN;
        xfall[ns][0] = *(const bf16x8*)(xb + hi4 * 8);
        xfall[ns][1] = *(const bf16x8*)(xb + 32 + hi4 * 8);
    }

    // ---- phase B: ppf + edge_attr for own slot -----------------------------
    int jme = nbrlist[l];
    int jc = max(jme, 0);
    float4 ni4 = nrm4[p];
    float4 pj4 = pos4[jc];
    float4 nj4 = nrm4[jc];
    float nxi = ni4.x, nyi = ni4.y, nzi = ni4.z;
    float nxj = nj4.x, nyj = nj4.y, nzj = nj4.z;
    float vx = pj4.x - pxi, vy = pj4.y - pyi, vz = pj4.z - pzi;
    float sq = vx * vx + vy * vy + vz * vz;
    float dd = sq > 0.0f ? sqrtf(sq) : 0.0f;
    float a1 = angle3(nxi, nyi, nzi, vx, vy, vz);
    float a2 = angle3(nxj, nyj, nzj, vx, vy, vz);
    float a3 = angle3(nxi, nyi, nzi, nxj, nyj, nzj);
    // edge match: scan bucket[p] (wave-uniform base), min-e over src==j
    unsigned eidx = E_G;   // sentinel row
    {
        const u64* bp = bkt + (size_t)p * BCAP;
        int bc = min((int)bcnt[p], BCAP);
        for (int u0 = 0; u0 < bc; u0 += 4) {
            u64 e0 = bp[u0];
            u64 e1 = (u0 + 1 < bc) ? bp[u0 + 1] : 0xFFFFFFFFFFFFFFFFull;
            u64 e2 = (u0 + 2 < bc) ? bp[u0 + 2] : 0xFFFFFFFFFFFFFFFFull;
            u64 e3 = (u0 + 3 < bc) ? bp[u0 + 3] : 0xFFFFFFFFFFFFFFFFull;
            if ((int)(e0 >> 32) == jc) eidx = min(eidx, (unsigned)e0);
            if ((int)(e1 >> 32) == jc) eidx = min(eidx, (unsigned)e1);
            if ((int)(e2 >> 32) == jc) eidx = min(eidx, (unsigned)e2);
            if ((int)(e3 >> 32) == jc) eidx = min(eidx, (unsigned)e3);
        }
    }
    float4 er = *(const float4*)(edge_attr + (size_t)eidx * D_E);
    int4 pk;
    pk.x = (int)pack2bf(dd, a1);   pk.y = (int)pack2bf(a2, a3);
    pk.z = (int)pack2bf(er.x, er.y); pk.w = (int)pack2bf(er.z, er.w);
    ((int4*)pkrow)[l] = pk;

    // ---- layer 1: D1[c1][slot] = W1^T @ msg^T; LDS-chunk reshuffle to haf --
    bf16x8 haf[4][4];   // [ms][kt]
    #pragma unroll
    for (int pass = 0; pass < 2; ++pass) {
        bf16x8 ktf[2];
        #pragma unroll
        for (int nsl = 0; nsl < 2; ++nsl) {
            int slot = (pass * 2 + nsl) * 16 + lo16;
            // kt=2 B-frag: f64..71 = ppf+eattr (hi4==0); f72 bias=1 (hi4==1)
            int4 q = ((const int4*)pkrow)[slot];
            union { bf16x8 v; u32 d[4]; } u;
            u.d[0] = hi4 == 0 ? (u32)q.x : (hi4 == 1 ? 0x3F80u : 0u);
            u.d[1] = hi4 == 0 ? (u32)q.y : 0u;
            u.d[2] = hi4 == 0 ? (u32)q.z : 0u;
            u.d[3] = hi4 == 0 ? (u32)q.w : 0u;
            ktf[nsl] = u.v;
        }
        #pragma unroll
        for (int mtp = 0; mtp < 4; ++mtp) {
            #pragma unroll
            for (int sub = 0; sub < 2; ++sub) {
                int mt = mtp * 2 + sub;
                bf16x8 af0 = *(const bf16x8*)(w1f + ((0 * 8 + mt) * 64 + l) * 8);
                bf16x8 af1 = *(const bf16x8*)(w1f + ((1 * 8 + mt) * 64 + l) * 8);
                bf16x8 af2 = *(const bf16x8*)(w1f + ((2 * 8 + mt) * 64 + l) * 8);
                #pragma unroll
                for (int nsl = 0; nsl < 2; ++nsl) {
                    f32x4 acc = (f32x4)0.0f;
                    acc = __builtin_amdgcn_mfma_f32_16x16x32_bf16(af0, xfall[pass * 2 + nsl][0], acc, 0, 0, 0);
                    acc = __builtin_amdgcn_mfma_f32_16x16x32_bf16(af1, xfall[pass * 2 + nsl][1], acc, 0, 0, 0);
                    acc = __builtin_amdgcn_mfma_f32_16x16x32_bf16(af2, ktf[nsl], acc, 0, 0, 0);
                    uint2 o;
                    o.x = pack2t(fmaxf(acc[0], 0.0f), fmaxf(acc[1], 0.0f));
                    o.y = pack2t(fmaxf(acc[2], 0.0f), fmaxf(acc[3], 0.0f));
                    *(uint2*)(cb + (nsl * 16 + lo16) * RSC + sub * 16 + hi4 * 4) = o;
                }
            }
            #pragma unroll
            for (int nsl = 0; nsl < 2; ++nsl)
                haf[pass * 2 + nsl][mtp] =
                    *(const bf16x8*)(cb + (nsl * 16 + lo16) * RSC + hi4 * 8);
        }
    }

    // ---- layer 2: D2[slot][c2] = h1 @ W2 (+b2); masked relu-max over slots -
    #pragma unroll
    for (int nt = 0; nt < 8; ++nt) {
        float bb = b2[nt * 16 + lo16];
        f32x4 acc[4];
        #pragma unroll
        for (int ms = 0; ms < 4; ++ms) { f32x4 bv = {bb, bb, bb, bb}; acc[ms] = bv; }
        #pragma unroll
        for (int kt = 0; kt < 4; ++kt) {
            bf16x8 bfr = *(const bf16x8*)(w2f + ((kt * 8 + nt) * 64 + l) * 8);
            #pragma unroll
            for (int ms = 0; ms < 4; ++ms)
                acc[ms] = __builtin_amdgcn_mfma_f32_16x16x32_bf16(haf[ms][kt], bfr, acc[ms], 0, 0, 0);
        }
        // m starts at 0: max over valid of relu == max(0, max over valid)
        float m = 0.0f;
        #pragma unroll
        for (int ms = 0; ms < 4; ++ms)
            #pragma unroll
            for (int r = 0; r < 4; ++r) {
                int slot = ms * 16 + hi4 * 4 + r;
                m = fmaxf(m, slot < cnt ? acc[ms][r] : 0.0f);
            }
        m = fmaxf(m, __shfl_xor(m, 16, 64));
        m = fmaxf(m, __shfl_xor(m, 32, 64));
        if ((nt >> 1) == hi4)
            aggbf[w * ARS + nt * 16 + lo16] =
                (unsigned short)(__float_as_uint(m) >> 16);
    }

    // ---- fused global_nn: out[4 pts][128] = agg @ Wg + bg ------------------
    __syncthreads();
    int arow = lo16 & 3;
    bf16x8 afr2[4];
    #pragma unroll
    for (int kt = 0; kt < 4; ++kt)
        afr2[kt] = *(const bf16x8*)(aggbf + arow * ARS + kt * 32 + hi4 * 8);
    int ntA = w * 2, ntB = w * 2 + 1;
    f32x4 accA = (f32x4)0.0f, accB = (f32x4)0.0f;
    #pragma unroll
    for (int kt = 0; kt < 4; ++kt) {
        bf16x8 bfrA = *(const bf16x8*)(wgf + ((kt * 8 + ntA) * 64 + l) * 8);
        bf16x8 bfrB = *(const bf16x8*)(wgf + ((kt * 8 + ntB) * 64 + l) * 8);
        accA = __builtin_amdgcn_mfma_f32_16x16x32_bf16(afr2[kt], bfrA, accA, 0, 0, 0);
        accB = __builtin_amdgcn_mfma_f32_16x16x32_bf16(afr2[kt], bfrB, accB, 0, 0, 0);
    }
    if (hi4 == 0) {   // C rows 0..3 = points 0..3
        int cA = ntA * 16 + lo16, cB = ntB * 16 + lo16;
        float bgA = bg[cA], bgB = bg[cB];
        size_t obase = (size_t)(blockIdx.x * 4) * OUT_DIM;
        #pragma unroll
        for (int r = 0; r < 4; ++r) {
            out[obase + (size_t)r * OUT_DIM + cA] = accA[r] + bgA;
            out[obase + (size_t)r * OUT_DIM + cB] = accB[r] + bgB;
        }
    }
}

// ---------------------------------------------------------------------------
extern "C" void kernel_launch(void* const* d_in, const int* in_sizes, int n_in,
                              void* d_out, int out_size, void* d_ws, size_t ws_size,
                              hipStream_t stream) {
    const float* x         = (const float*)d_in[0];
    const float* pos       = (const float*)d_in[1];
    const float* normal    = (const float*)d_in[2];
    const int*   batch     = (const int*)d_in[3];
    const float* edge_attr = (const float*)d_in[4];
    const int*   edge_index= (const int*)d_in[5];
    const float* W1        = (const float*)d_in[6];
    const float* b1        = (const float*)d_in[7];
    const float* W2        = (const float*)d_in[8];
    const float* b2        = (const float*)d_in[9];
    const float* Wg        = (const float*)d_in[10];
    const float* bg        = (const float*)d_in[11];
    float* out = (float*)d_out;

    unsigned char* wsb = (unsigned char*)d_ws;
    u32* bcnt = (u32*)wsb;                                      // 32 KB
    u64* bkt  = (u64*)(wsb + (size_t)N_PTS * 4);                // 5.24 MB
    unsigned short* w1f = (unsigned short*)((unsigned char*)bkt +
                          (size_t)N_PTS * BCAP * 8);
    unsigned short* w2f = w1f + 12288;
    unsigned short* wgf = w2f + 16384;
    unsigned short* xbf = wgf + 16384;                          // 1 MB
    float4* pos4 = (float4*)(xbf + (size_t)N_PTS * F_IN);       // 128 KB
    float4* nrm4 = pos4 + N_PTS;                                // 128 KB
    int* bounds = (int*)(nrm4 + N_PTS);

    hipMemsetAsync(bcnt, 0, (size_t)N_PTS * 4, stream);

    setup_kernel<<<E_G / 256 + 256 + 128, 256, 0, stream>>>(
        edge_index, bcnt, bkt, W1, b1, W2, Wg, x, pos, normal, batch, bounds,
        w1f, w2f, wgf, xbf, pos4, nrm4, out);
    mlp_kernel<<<N_PTS / 4, 256, 0, stream>>>(xbf, pos4, nrm4, edge_attr,
                                              bcnt, bkt, batch, bounds,
                                              w1f, w2f, wgf, b2, bg, out);
}